// Round 8
// baseline (205.701 us; speedup 1.0000x reference)
//
#include <hip/hip_runtime.h>
#include <hip/hip_bf16.h>

#define TWO_B 8192
#define HALF_B 4096
#define DIM 128
#define RPB 16
#define THREADS 1024
#define NWAVES (THREADS / 64)  // 16
#define KTOP 4095
// z scaled by sqrt((1/T)*log2(e)) -> MFMA output w = sim/T*log2(e); exp(sim/T)=exp2(w)
#define NRM_SCALE2 4.5398159f
#define LN2 0.69314718f
#define WLO (-0.28853900f)
#define WHI (0.28853900f)
#define NBINS 256
#define BIN_SCALE ((float)NBINS / (WHI - WLO))
#define INV_BIN_SCALE ((WHI - WLO) / (float)NBINS)
#define BIN_BIAS (-(WLO)*BIN_SCALE)

#define EXP2F(x) __builtin_amdgcn_exp2f(x)

typedef __bf16 bf16x8 __attribute__((ext_vector_type(8)));
typedef float f32x4 __attribute__((ext_vector_type(4)));

// ---- kernel 1: L2-normalize rows of z1,z2, scale by sqrt(log2e/T) -> bf16 z [8192][128] ----
__global__ __launch_bounds__(256) void nrm_kernel(const float* __restrict__ z1,
                                                  const float* __restrict__ z2,
                                                  ushort* __restrict__ zb) {
    const int lane = threadIdx.x & 63;
    const int row = blockIdx.x * 4 + (threadIdx.x >> 6);
    const float* src = (row < HALF_B) ? (z1 + (size_t)row * DIM)
                                      : (z2 + (size_t)(row - HALF_B) * DIM);
    float2 v = *reinterpret_cast<const float2*>(src + lane * 2);
    float ss = v.x * v.x + v.y * v.y;
#pragma unroll
    for (int off = 32; off; off >>= 1) ss += __shfl_xor(ss, off);
    const float inv = NRM_SCALE2 / fmaxf(sqrtf(ss), 1e-12f);
    __hip_bfloat16 a = __float2bfloat16(v.x * inv);
    __hip_bfloat16 b = __float2bfloat16(v.y * inv);
    ushort2 st;
    st.x = *reinterpret_cast<ushort*>(&a);
    st.y = *reinterpret_cast<ushort*>(&b);
    *reinterpret_cast<ushort2*>(zb + (size_t)row * DIM + lane * 2) = st;
}

// ---- kernel 2: 16 rows/block, 512 blocks (2/CU): count-only windowed histogram ----
__global__ __launch_bounds__(THREADS, 8) void ntxent_kernel(const ushort* __restrict__ zb,
                                                            float* __restrict__ out) {
    __shared__ unsigned cntS[RPB / 2][NBINS + 1];  // u16-packed per-row-pair bin counts
    __shared__ float chunkF[RPB][16];
    __shared__ unsigned chunkC[RPB][16];
    __shared__ float sumHiS[RPB];
    __shared__ unsigned cntHiS[RPB];
    __shared__ float posS[RPB];

    const int tid = threadIdx.x;
    const int lane = tid & 63;
    const int wave = tid >> 6;
    const int rowbase = blockIdx.x * RPB;

    for (int i = tid; i < (RPB / 2) * (NBINS + 1); i += THREADS) (&cntS[0][0])[i] = 0u;
    if (tid < RPB) { sumHiS[tid] = 0.f; cntHiS[tid] = 0u; posS[tid] = 0.f; }
    __syncthreads();

    const int frow = lane & 15;
    const int kbase = (lane >> 4) * 8;
    const int drow = (lane >> 4) * 4;
    const int spD = rowbase;           // chunk containing the diagonal
    const int spP = rowbase ^ HALF_B;  // chunk containing the positives

    bf16x8 af[4];
    {
        const ushort* ap = zb + (size_t)(rowbase + frow) * DIM + kbase;
#pragma unroll
        for (int ks = 0; ks < 4; ++ks) af[ks] = *reinterpret_cast<const bf16x8*>(ap + ks * 32);
    }

    const ushort* zlane = zb + (size_t)frow * DIM + kbase;

#define COL16(J) (((J) >> 1) * (NWAVES * 32) + wave * 32 + (((J) & 1) << 4))

#define LOADF(DST, J)                                                            \
    {                                                                            \
        const ushort* _p = zlane + (size_t)COL16(J) * DIM;                       \
        _Pragma("unroll") for (int ks = 0; ks < 4; ++ks)                         \
            DST[ks] = *reinterpret_cast<const bf16x8*>(_p + ks * 32);            \
    }

#define MFMA4(BUF, ACC)                                                          \
    _Pragma("unroll") for (int ks = 0; ks < 4; ++ks) {                           \
        ACC = __builtin_amdgcn_mfma_f32_16x16x32_bf16(af[ks], BUF[ks], ACC, 0, 0, 0); \
    }

    unsigned cntHi = 0u;  // packed 4x8-bit high-count
    float sHi[4] = {0.f, 0.f, 0.f, 0.f};

#define EPI(ACC, COL, CHK)                                                       \
    _Pragma("unroll") for (int rg = 0; rg < 4; ++rg) {                           \
        const int grow = rowbase + drow + rg;                                    \
        const float v = ACC[rg];                                                 \
        bool use = true;                                                         \
        if (CHK) {                                                               \
            if ((COL) == grow) use = false;                                      \
            if ((COL) == (grow ^ HALF_B)) posS[drow + rg] = v;                   \
        }                                                                        \
        if (use) {                                                               \
            const float t = fmaf(v, BIN_SCALE, BIN_BIAS);                        \
            if (t >= (float)NBINS) {                                             \
                sHi[rg] += EXP2F(v);                                             \
                cntHi += (1u << (8 * rg));                                       \
            } else if (t >= 0.f) {                                               \
                const int bin = (int)t;                                          \
                atomicAdd(&cntS[(drow + rg) >> 1][bin], 1u << (16 * (rg & 1)));  \
            }                                                                    \
        }                                                                        \
    }

#define BODY(BUF, J)                                                             \
    {                                                                            \
        f32x4 acc = {0.f, 0.f, 0.f, 0.f};                                        \
        MFMA4(BUF, acc)                                                          \
        const int c16 = COL16(J);                                                \
        const int col = c16 + frow;                                              \
        if (c16 == spD || c16 == spP) {                                          \
            EPI(acc, col, true)                                                  \
        } else {                                                                 \
            EPI(acc, col, false)                                                 \
        }                                                                        \
    }

    bf16x8 bufA[4], bufB[4];
    LOADF(bufA, 0)
    for (int j = 0; j < 32; j += 2) {
        LOADF(bufB, j + 1)
        BODY(bufA, j)
        if (j + 2 < 32) LOADF(bufA, j + 2)
        BODY(bufB, j + 1)
    }

    // reduce high-count and high-sum across the 16 lanes sharing each row group
    {
        unsigned c[4];
        float f[4];
#pragma unroll
        for (int rg = 0; rg < 4; ++rg) {
            c[rg] = (cntHi >> (8 * rg)) & 0xffu;
            f[rg] = sHi[rg];
        }
#pragma unroll
        for (int rg = 0; rg < 4; ++rg) {
#pragma unroll
            for (int s = 1; s < 16; s <<= 1) {
                c[rg] += __shfl_xor(c[rg], s);
                f[rg] += __shfl_xor(f[rg], s);
            }
        }
        if ((lane & 15) == 0) {
#pragma unroll
            for (int rg = 0; rg < 4; ++rg) {
                atomicAdd(&cntHiS[drow + rg], c[rg]);
                atomicAdd(&sumHiS[drow + rg], f[rg]);
            }
        }
    }
    __syncthreads();

    // ---- per-row chunk sums (16 chunks of 16 bins, top-down) ----
    if (tid < RPB * 16) {
        const int row = tid >> 4, c = tid & 15;
        const int btop = NBINS - 1 - c * 16;
        unsigned s = 0;
        float fs = 0.f;
#pragma unroll
        for (int t = 0; t < 16; ++t) {
            const unsigned w = cntS[row >> 1][btop - t];
            const unsigned h = (w >> (16 * (row & 1))) & 0xffffu;
            s += h;
            fs += (float)h * EXP2F(WLO + ((float)(btop - t) + 0.5f) * INV_BIN_SCALE);
        }
        chunkC[row][c] = s;
        chunkF[row][c] = fs;
    }
    __syncthreads();

    // ---- per-row threshold + hard-negative sum + loss ----
    if (tid < RPB) {
        const int row = tid;
        unsigned cum = cntHiS[row];
        float fAbove = sumHiS[row];
        float radd = 0.f;
        if (cum < (unsigned)KTOP) {
            int c = 0;
            for (; c < 16; ++c) {
                const unsigned cs = chunkC[row][c];
                if (cum + cs >= (unsigned)KTOP) break;
                cum += cs;
                fAbove += chunkF[row][c];
            }
            if (c < 16) {
                const int btop = NBINS - 1 - c * 16;
                for (int t = 0; t < 16; ++t) {
                    const unsigned w = cntS[row >> 1][btop - t];
                    const unsigned h = (w >> (16 * (row & 1))) & 0xffffu;
                    const float em = EXP2F(WLO + ((float)(btop - t) + 0.5f) * INV_BIN_SCALE);
                    if (cum + h >= (unsigned)KTOP) {
                        radd = (float)(KTOP - cum) * em;
                        break;
                    }
                    cum += h;
                    fAbove += (float)h * em;
                }
            }
        }
        const float hns = fAbove + radd;
        const float wpos = posS[row];
        float loss = logf(EXP2F(wpos) + hns) - wpos * LN2;
#pragma unroll
        for (int s = 1; s < 16; s <<= 1) loss += __shfl_xor(loss, s);
        if (tid == 0) atomicAdd(out, loss * (1.0f / (float)TWO_B));
    }
}

extern "C" void kernel_launch(void* const* d_in, const int* in_sizes, int n_in,
                              void* d_out, int out_size, void* d_ws, size_t ws_size,
                              hipStream_t stream) {
    const float* z1 = (const float*)d_in[0];
    const float* z2 = (const float*)d_in[1];
    float* out = (float*)d_out;
    ushort* zb = (ushort*)d_ws;  // 8192*128*2 = 2 MB

    hipMemsetAsync(d_out, 0, sizeof(float), stream);
    nrm_kernel<<<TWO_B / 4, 256, 0, stream>>>(z1, z2, zb);
    ntxent_kernel<<<TWO_B / RPB, THREADS, 0, stream>>>(zb, out);
}

// Round 9
// 130.179 us; speedup vs baseline: 1.5801x; 1.5801x over previous
//
#include <hip/hip_runtime.h>
#include <hip/hip_bf16.h>

#define TWO_B 8192
#define HALF_B 4096
#define DIM 128
#define RPB 32
#define THREADS 1024
#define NWAVES (THREADS / 64)
#define KTOP 4095
// z scaled by sqrt((1/T)*log2(e)) -> MFMA output w = sim/T*log2(e); exp(sim/T)=exp2(w)
#define NRM_SCALE2 4.5398159f
#define LN2 0.69314718f
#define WLO (-0.28853900f)
#define WHI (0.28853900f)
#define NBINS 256
#define BIN_SCALE ((float)NBINS / (WHI - WLO))
#define INV_BIN_SCALE ((WHI - WLO) / (float)NBINS)
#define BIN_BIAS (-(WLO)*BIN_SCALE)

#define EXP2F(x) __builtin_amdgcn_exp2f(x)

typedef __bf16 bf16x8 __attribute__((ext_vector_type(8)));
typedef float f32x4 __attribute__((ext_vector_type(4)));

// ---- kernel 1: L2-normalize rows of z1,z2, scale by sqrt(log2e/T) -> bf16 z [8192][128] ----
__global__ __launch_bounds__(256) void nrm_kernel(const float* __restrict__ z1,
                                                  const float* __restrict__ z2,
                                                  ushort* __restrict__ zb) {
    const int lane = threadIdx.x & 63;
    const int row = blockIdx.x * 4 + (threadIdx.x >> 6);
    const float* src = (row < HALF_B) ? (z1 + (size_t)row * DIM)
                                      : (z2 + (size_t)(row - HALF_B) * DIM);
    float2 v = *reinterpret_cast<const float2*>(src + lane * 2);
    float ss = v.x * v.x + v.y * v.y;
#pragma unroll
    for (int off = 32; off; off >>= 1) ss += __shfl_xor(ss, off);
    const float inv = NRM_SCALE2 / fmaxf(sqrtf(ss), 1e-12f);
    __hip_bfloat16 a = __float2bfloat16(v.x * inv);
    __hip_bfloat16 b = __float2bfloat16(v.y * inv);
    ushort2 st;
    st.x = *reinterpret_cast<ushort*>(&a);
    st.y = *reinterpret_cast<ushort*>(&b);
    *reinterpret_cast<ushort2*>(zb + (size_t)row * DIM + lane * 2) = st;
}

// ---- kernel 2: 32 rows/block; count-only windowed histogram, single GEMM pass ----
// NOTE: no min-waves clause — R7/R8 showed any VGPR constraint here spills
// the register pipeline to scratch (WRITE_SIZE 8KB -> 10-36MB). VGPR 56 natural.
__global__ __launch_bounds__(THREADS) void ntxent_kernel(const ushort* __restrict__ zb,
                                                         float* __restrict__ out) {
    __shared__ unsigned cntS[RPB / 2][NBINS + 1];  // u16-packed per-row-pair bin counts
    __shared__ float chunkF[RPB][16];
    __shared__ unsigned chunkC[RPB][16];
    __shared__ float sumHiS[RPB];
    __shared__ unsigned cntHiS[RPB];
    __shared__ float posS[RPB];

    const int tid = threadIdx.x;
    const int lane = tid & 63;
    const int wave = tid >> 6;
    const int rowbase = blockIdx.x * RPB;

    for (int i = tid; i < (RPB / 2) * (NBINS + 1); i += THREADS) (&cntS[0][0])[i] = 0u;
    if (tid < RPB) { sumHiS[tid] = 0.f; cntHiS[tid] = 0u; posS[tid] = 0.f; }
    __syncthreads();

    const int frow = lane & 15;
    const int kbase = (lane >> 4) * 8;
    const int drow = (lane >> 4) * 4;
    const int sp0 = rowbase, sp1 = rowbase + 16;
    const int sp2 = rowbase ^ HALF_B, sp3 = sp2 + 16;

    bf16x8 afL[4], afH[4];
    {
        const ushort* aL = zb + (size_t)(rowbase + frow) * DIM + kbase;
#pragma unroll
        for (int ks = 0; ks < 4; ++ks) {
            afL[ks] = *reinterpret_cast<const bf16x8*>(aL + ks * 32);
            afH[ks] = *reinterpret_cast<const bf16x8*>(aL + 16 * DIM + ks * 32);
        }
    }

    const ushort* zlane = zb + (size_t)frow * DIM + kbase;

#define COL16(J) (((J) >> 1) * (NWAVES * 32) + wave * 32 + (((J) & 1) << 4))

#define LOADF(DST, J)                                                            \
    {                                                                            \
        const ushort* _p = zlane + (size_t)COL16(J) * DIM;                       \
        _Pragma("unroll") for (int ks = 0; ks < 4; ++ks)                         \
            DST[ks] = *reinterpret_cast<const bf16x8*>(_p + ks * 32);            \
    }

#define MFMA8(BUF, ACCL, ACCH)                                                   \
    _Pragma("unroll") for (int ks = 0; ks < 4; ++ks) {                           \
        ACCL = __builtin_amdgcn_mfma_f32_16x16x32_bf16(afL[ks], BUF[ks], ACCL, 0, 0, 0); \
        ACCH = __builtin_amdgcn_mfma_f32_16x16x32_bf16(afH[ks], BUF[ks], ACCH, 0, 0, 0); \
    }

    unsigned cntL = 0u, cntH = 0u;  // packed 4x8-bit high-count (max 32 each)
    float sHiL[4] = {0.f, 0.f, 0.f, 0.f}, sHiH[4] = {0.f, 0.f, 0.f, 0.f};

#define EPI(ACCL, ACCH, COL, CHK)                                                \
    _Pragma("unroll") for (int rg = 0; rg < 4; ++rg) {                           \
        const int growL = rowbase + drow + rg;                                   \
        const float vL = ACCL[rg];                                               \
        const float vH = ACCH[rg];                                               \
        bool useL = true, useH = true;                                           \
        if (CHK) {                                                               \
            if ((COL) == growL) useL = false;                                    \
            if ((COL) == growL + 16) useH = false;                               \
            if ((COL) == (growL ^ HALF_B)) posS[drow + rg] = vL;                 \
            if ((COL) == ((growL + 16) ^ HALF_B)) posS[drow + rg + 16] = vH;     \
        }                                                                        \
        if (useL) {                                                              \
            const float t = fmaf(vL, BIN_SCALE, BIN_BIAS);                       \
            if (t >= (float)NBINS) {                                             \
                sHiL[rg] += EXP2F(vL);                                           \
                cntL += (1u << (8 * rg));                                        \
            } else if (t >= 0.f) {                                               \
                const int bin = (int)t;                                          \
                atomicAdd(&cntS[(drow + rg) >> 1][bin], 1u << (16 * (rg & 1)));  \
            }                                                                    \
        }                                                                        \
        if (useH) {                                                              \
            const float t = fmaf(vH, BIN_SCALE, BIN_BIAS);                       \
            if (t >= (float)NBINS) {                                             \
                sHiH[rg] += EXP2F(vH);                                           \
                cntH += (1u << (8 * rg));                                        \
            } else if (t >= 0.f) {                                               \
                const int bin = (int)t;                                          \
                atomicAdd(&cntS[(drow + rg + 16) >> 1][bin], 1u << (16 * (rg & 1))); \
            }                                                                    \
        }                                                                        \
    }

#define BODY(BUF, J)                                                             \
    {                                                                            \
        f32x4 accL = {0.f, 0.f, 0.f, 0.f}, accH = {0.f, 0.f, 0.f, 0.f};          \
        MFMA8(BUF, accL, accH)                                                   \
        const int c16 = COL16(J);                                                \
        const int col = c16 + frow;                                              \
        if (c16 == sp0 || c16 == sp1 || c16 == sp2 || c16 == sp3) {              \
            EPI(accL, accH, col, true)                                           \
        } else {                                                                 \
            EPI(accL, accH, col, false)                                          \
        }                                                                        \
    }

    bf16x8 bufA[4], bufB[4];
    LOADF(bufA, 0)
    for (int j = 0; j < 32; j += 2) {
        LOADF(bufB, j + 1)
        BODY(bufA, j)
        if (j + 2 < 32) LOADF(bufA, j + 2)
        BODY(bufB, j + 1)
    }

    // reduce high-count and high-sum across the 16 lanes sharing each row
    {
        unsigned c[8];
        float f[8];
#pragma unroll
        for (int rg = 0; rg < 4; ++rg) {
            c[rg] = (cntL >> (8 * rg)) & 0xffu;
            c[rg + 4] = (cntH >> (8 * rg)) & 0xffu;
            f[rg] = sHiL[rg];
            f[rg + 4] = sHiH[rg];
        }
#pragma unroll
        for (int r = 0; r < 8; ++r) {
#pragma unroll
            for (int s = 1; s < 16; s <<= 1) {
                c[r] += __shfl_xor(c[r], s);
                f[r] += __shfl_xor(f[r], s);
            }
        }
        if ((lane & 15) == 0) {
#pragma unroll
            for (int r = 0; r < 4; ++r) {
                atomicAdd(&cntHiS[drow + r], c[r]);
                atomicAdd(&cntHiS[drow + r + 16], c[r + 4]);
                atomicAdd(&sumHiS[drow + r], f[r]);
                atomicAdd(&sumHiS[drow + r + 16], f[r + 4]);
            }
        }
    }
    __syncthreads();

    // ---- per-row chunk sums (16 chunks of 16 bins, top-down); exp reconstructed
    //      from counts at bin midpoints ----
    if (tid < RPB * 16) {
        const int row = tid >> 4, c = tid & 15;
        const int btop = NBINS - 1 - c * 16;
        unsigned s = 0;
        float fs = 0.f;
#pragma unroll
        for (int t = 0; t < 16; ++t) {
            const unsigned w = cntS[row >> 1][btop - t];
            const unsigned h = (w >> (16 * (row & 1))) & 0xffffu;
            s += h;
            fs += (float)h * EXP2F(WLO + ((float)(btop - t) + 0.5f) * INV_BIN_SCALE);
        }
        chunkC[row][c] = s;
        chunkF[row][c] = fs;
    }
    __syncthreads();

    // ---- per-row threshold + hard-negative sum + loss ----
    if (tid < RPB) {
        const int row = tid;
        unsigned cum = cntHiS[row];
        float fAbove = sumHiS[row];
        float radd = 0.f;
        if (cum < (unsigned)KTOP) {
            int c = 0;
            for (; c < 16; ++c) {
                const unsigned cs = chunkC[row][c];
                if (cum + cs >= (unsigned)KTOP) break;
                cum += cs;
                fAbove += chunkF[row][c];
            }
            if (c < 16) {
                const int btop = NBINS - 1 - c * 16;
                for (int t = 0; t < 16; ++t) {
                    const unsigned w = cntS[row >> 1][btop - t];
                    const unsigned h = (w >> (16 * (row & 1))) & 0xffffu;
                    const float em = EXP2F(WLO + ((float)(btop - t) + 0.5f) * INV_BIN_SCALE);
                    if (cum + h >= (unsigned)KTOP) {
                        radd = (float)(KTOP - cum) * em;
                        break;
                    }
                    cum += h;
                    fAbove += (float)h * em;
                }
            }
        }
        const float hns = fAbove + radd;
        const float wpos = posS[row];
        float loss = logf(EXP2F(wpos) + hns) - wpos * LN2;
#pragma unroll
        for (int s = 1; s < 32; s <<= 1) loss += __shfl_xor(loss, s);
        if (tid == 0) atomicAdd(out, loss * (1.0f / (float)TWO_B));
    }
}

extern "C" void kernel_launch(void* const* d_in, const int* in_sizes, int n_in,
                              void* d_out, int out_size, void* d_ws, size_t ws_size,
                              hipStream_t stream) {
    const float* z1 = (const float*)d_in[0];
    const float* z2 = (const float*)d_in[1];
    float* out = (float*)d_out;
    ushort* zb = (ushort*)d_ws;  // 8192*128*2 = 2 MB

    hipMemsetAsync(d_out, 0, sizeof(float), stream);
    nrm_kernel<<<TWO_B / 4, 256, 0, stream>>>(z1, z2, zb);
    ntxent_kernel<<<TWO_B / RPB, THREADS, 0, stream>>>(zb, out);
}

// Round 10
// 129.892 us; speedup vs baseline: 1.5836x; 1.0022x over previous
//
#include <hip/hip_runtime.h>
#include <hip/hip_bf16.h>

#define TWO_B 8192
#define HALF_B 4096
#define DIM 128
#define RPB 32
#define THREADS 1024
#define NWAVES (THREADS / 64)
#define KTOP 4095
// z scaled by sqrt((1/T)*log2(e)) -> MFMA output w = sim/T*log2(e); exp(sim/T)=exp2(w)
#define NRM_SCALE2 4.5398159f
#define LN2 0.69314718f
#define WLO (-0.28853900f)
#define WHI (0.28853900f)
#define NBINS 256
#define BIN_SCALE ((float)NBINS / (WHI - WLO))
#define INV_BIN_SCALE ((WHI - WLO) / (float)NBINS)
#define BIN_BIAS (-(WLO)*BIN_SCALE)

#define EXP2F(x) __builtin_amdgcn_exp2f(x)
#define SB __builtin_amdgcn_sched_barrier(0);

typedef __bf16 bf16x8 __attribute__((ext_vector_type(8)));
typedef float f32x4 __attribute__((ext_vector_type(4)));

// ---- kernel 1: L2-normalize rows of z1,z2, scale by sqrt(log2e/T) -> bf16 z [8192][128] ----
__global__ __launch_bounds__(256) void nrm_kernel(const float* __restrict__ z1,
                                                  const float* __restrict__ z2,
                                                  ushort* __restrict__ zb) {
    const int lane = threadIdx.x & 63;
    const int row = blockIdx.x * 4 + (threadIdx.x >> 6);
    const float* src = (row < HALF_B) ? (z1 + (size_t)row * DIM)
                                      : (z2 + (size_t)(row - HALF_B) * DIM);
    float2 v = *reinterpret_cast<const float2*>(src + lane * 2);
    float ss = v.x * v.x + v.y * v.y;
#pragma unroll
    for (int off = 32; off; off >>= 1) ss += __shfl_xor(ss, off);
    const float inv = NRM_SCALE2 / fmaxf(sqrtf(ss), 1e-12f);
    __hip_bfloat16 a = __float2bfloat16(v.x * inv);
    __hip_bfloat16 b = __float2bfloat16(v.y * inv);
    ushort2 st;
    st.x = *reinterpret_cast<ushort*>(&a);
    st.y = *reinterpret_cast<ushort*>(&b);
    *reinterpret_cast<ushort2*>(zb + (size_t)row * DIM + lane * 2) = st;
}

// ---- kernel 2: 32 rows/block; count-only windowed histogram, single GEMM pass ----
// NOTE: plain __launch_bounds__ — R7/R8 spills came from the min-waves VGPR cap
// (64/32), not from sched_barrier. Allocator free => cap 128 at 1024 threads.
__global__ __launch_bounds__(THREADS) void ntxent_kernel(const ushort* __restrict__ zb,
                                                         float* __restrict__ out) {
    __shared__ unsigned cntS[RPB / 2][NBINS + 1];  // u16-packed per-row-pair bin counts
    __shared__ float chunkF[RPB][16];
    __shared__ unsigned chunkC[RPB][16];
    __shared__ float sumHiS[RPB];
    __shared__ unsigned cntHiS[RPB];
    __shared__ float posS[RPB];

    const int tid = threadIdx.x;
    const int lane = tid & 63;
    const int wave = tid >> 6;
    const int rowbase = blockIdx.x * RPB;

    for (int i = tid; i < (RPB / 2) * (NBINS + 1); i += THREADS) (&cntS[0][0])[i] = 0u;
    if (tid < RPB) { sumHiS[tid] = 0.f; cntHiS[tid] = 0u; posS[tid] = 0.f; }
    __syncthreads();

    const int frow = lane & 15;
    const int kbase = (lane >> 4) * 8;
    const int drow = (lane >> 4) * 4;
    const int sp0 = rowbase, sp1 = rowbase + 16;
    const int sp2 = rowbase ^ HALF_B, sp3 = sp2 + 16;

    bf16x8 afL[4], afH[4];
    {
        const ushort* aL = zb + (size_t)(rowbase + frow) * DIM + kbase;
#pragma unroll
        for (int ks = 0; ks < 4; ++ks) {
            afL[ks] = *reinterpret_cast<const bf16x8*>(aL + ks * 32);
            afH[ks] = *reinterpret_cast<const bf16x8*>(aL + 16 * DIM + ks * 32);
        }
    }

    const ushort* zlane = zb + (size_t)frow * DIM + kbase;

#define COL16(J) (((J) >> 1) * (NWAVES * 32) + wave * 32 + (((J) & 1) << 4))

#define LOADF(DST, J)                                                            \
    {                                                                            \
        const ushort* _p = zlane + (size_t)COL16(J) * DIM;                       \
        _Pragma("unroll") for (int ks = 0; ks < 4; ++ks)                         \
            DST[ks] = *reinterpret_cast<const bf16x8*>(_p + ks * 32);            \
    }

#define MFMA8(BUF, ACCL, ACCH)                                                   \
    _Pragma("unroll") for (int ks = 0; ks < 4; ++ks) {                           \
        ACCL = __builtin_amdgcn_mfma_f32_16x16x32_bf16(afL[ks], BUF[ks], ACCL, 0, 0, 0); \
        ACCH = __builtin_amdgcn_mfma_f32_16x16x32_bf16(afH[ks], BUF[ks], ACCH, 0, 0, 0); \
    }

    unsigned cntL = 0u, cntH = 0u;  // packed 4x8-bit high-count (max 32 each)
    float sHiL[4] = {0.f, 0.f, 0.f, 0.f}, sHiH[4] = {0.f, 0.f, 0.f, 0.f};

#define EPI(ACCL, ACCH, COL, CHK)                                                \
    _Pragma("unroll") for (int rg = 0; rg < 4; ++rg) {                           \
        const int growL = rowbase + drow + rg;                                   \
        const float vL = ACCL[rg];                                               \
        const float vH = ACCH[rg];                                               \
        bool useL = true, useH = true;                                           \
        if (CHK) {                                                               \
            if ((COL) == growL) useL = false;                                    \
            if ((COL) == growL + 16) useH = false;                               \
            if ((COL) == (growL ^ HALF_B)) posS[drow + rg] = vL;                 \
            if ((COL) == ((growL + 16) ^ HALF_B)) posS[drow + rg + 16] = vH;     \
        }                                                                        \
        if (useL) {                                                              \
            const float t = fmaf(vL, BIN_SCALE, BIN_BIAS);                       \
            if (t >= (float)NBINS) {                                             \
                sHiL[rg] += EXP2F(vL);                                           \
                cntL += (1u << (8 * rg));                                        \
            } else if (t >= 0.f) {                                               \
                const int bin = (int)t;                                          \
                atomicAdd(&cntS[(drow + rg) >> 1][bin], 1u << (16 * (rg & 1)));  \
            }                                                                    \
        }                                                                        \
        if (useH) {                                                              \
            const float t = fmaf(vH, BIN_SCALE, BIN_BIAS);                       \
            if (t >= (float)NBINS) {                                             \
                sHiH[rg] += EXP2F(vH);                                           \
                cntH += (1u << (8 * rg));                                        \
            } else if (t >= 0.f) {                                               \
                const int bin = (int)t;                                          \
                atomicAdd(&cntS[(drow + rg + 16) >> 1][bin], 1u << (16 * (rg & 1))); \
            }                                                                    \
        }                                                                        \
    }

#define BODY(BUF, J)                                                             \
    {                                                                            \
        f32x4 accL = {0.f, 0.f, 0.f, 0.f}, accH = {0.f, 0.f, 0.f, 0.f};          \
        MFMA8(BUF, accL, accH)                                                   \
        const int c16 = COL16(J);                                                \
        const int col = c16 + frow;                                              \
        if (c16 == sp0 || c16 == sp1 || c16 == sp2 || c16 == sp3) {              \
            EPI(accL, accH, col, true)                                           \
        } else {                                                                 \
            EPI(accL, accH, col, false)                                          \
        }                                                                        \
    }

    // 3-buffer, distance-2 pipeline. sched_barrier(0) after each LOADF keeps the
    // loads where they are issued (2 BODYs ~400cyc ahead of use). Rotation has
    // period 3 over a 3-body unrolled loop: state at loop head is always
    // b0 = tile j, b1 = tile j+1.
    bf16x8 b0[4], b1[4], b2[4];
    LOADF(b0, 0) SB
    LOADF(b1, 1) SB
    for (int j = 0; j < 30; j += 3) {
        LOADF(b2, j + 2) SB
        BODY(b0, j)
        LOADF(b0, j + 3) SB
        BODY(b1, j + 1)
        LOADF(b1, j + 4) SB
        BODY(b2, j + 2)
    }
    BODY(b0, 30)
    BODY(b1, 31)

    // reduce high-count and high-sum across the 16 lanes sharing each row
    {
        unsigned c[8];
        float f[8];
#pragma unroll
        for (int rg = 0; rg < 4; ++rg) {
            c[rg] = (cntL >> (8 * rg)) & 0xffu;
            c[rg + 4] = (cntH >> (8 * rg)) & 0xffu;
            f[rg] = sHiL[rg];
            f[rg + 4] = sHiH[rg];
        }
#pragma unroll
        for (int r = 0; r < 8; ++r) {
#pragma unroll
            for (int s = 1; s < 16; s <<= 1) {
                c[r] += __shfl_xor(c[r], s);
                f[r] += __shfl_xor(f[r], s);
            }
        }
        if ((lane & 15) == 0) {
#pragma unroll
            for (int r = 0; r < 4; ++r) {
                atomicAdd(&cntHiS[drow + r], c[r]);
                atomicAdd(&cntHiS[drow + r + 16], c[r + 4]);
                atomicAdd(&sumHiS[drow + r], f[r]);
                atomicAdd(&sumHiS[drow + r + 16], f[r + 4]);
            }
        }
    }
    __syncthreads();

    // ---- per-row chunk sums (16 chunks of 16 bins, top-down); exp reconstructed
    //      from counts at bin midpoints ----
    if (tid < RPB * 16) {
        const int row = tid >> 4, c = tid & 15;
        const int btop = NBINS - 1 - c * 16;
        unsigned s = 0;
        float fs = 0.f;
#pragma unroll
        for (int t = 0; t < 16; ++t) {
            const unsigned w = cntS[row >> 1][btop - t];
            const unsigned h = (w >> (16 * (row & 1))) & 0xffffu;
            s += h;
            fs += (float)h * EXP2F(WLO + ((float)(btop - t) + 0.5f) * INV_BIN_SCALE);
        }
        chunkC[row][c] = s;
        chunkF[row][c] = fs;
    }
    __syncthreads();

    // ---- per-row threshold + hard-negative sum + loss ----
    if (tid < RPB) {
        const int row = tid;
        unsigned cum = cntHiS[row];
        float fAbove = sumHiS[row];
        float radd = 0.f;
        if (cum < (unsigned)KTOP) {
            int c = 0;
            for (; c < 16; ++c) {
                const unsigned cs = chunkC[row][c];
                if (cum + cs >= (unsigned)KTOP) break;
                cum += cs;
                fAbove += chunkF[row][c];
            }
            if (c < 16) {
                const int btop = NBINS - 1 - c * 16;
                for (int t = 0; t < 16; ++t) {
                    const unsigned w = cntS[row >> 1][btop - t];
                    const unsigned h = (w >> (16 * (row & 1))) & 0xffffu;
                    const float em = EXP2F(WLO + ((float)(btop - t) + 0.5f) * INV_BIN_SCALE);
                    if (cum + h >= (unsigned)KTOP) {
                        radd = (float)(KTOP - cum) * em;
                        break;
                    }
                    cum += h;
                    fAbove += (float)h * em;
                }
            }
        }
        const float hns = fAbove + radd;
        const float wpos = posS[row];
        float loss = logf(EXP2F(wpos) + hns) - wpos * LN2;
#pragma unroll
        for (int s = 1; s < 32; s <<= 1) loss += __shfl_xor(loss, s);
        if (tid == 0) atomicAdd(out, loss * (1.0f / (float)TWO_B));
    }
}

extern "C" void kernel_launch(void* const* d_in, const int* in_sizes, int n_in,
                              void* d_out, int out_size, void* d_ws, size_t ws_size,
                              hipStream_t stream) {
    const float* z1 = (const float*)d_in[0];
    const float* z2 = (const float*)d_in[1];
    float* out = (float*)d_out;
    ushort* zb = (ushort*)d_ws;  // 8192*128*2 = 2 MB

    hipMemsetAsync(d_out, 0, sizeof(float), stream);
    nrm_kernel<<<TWO_B / 4, 256, 0, stream>>>(z1, z2, zb);
    ntxent_kernel<<<TWO_B / RPB, THREADS, 0, stream>>>(zb, out);
}